// Round 10
// baseline (159.528 us; speedup 1.0000x reference)
//
#include <hip/hip_runtime.h>
#include <hip/hip_bf16.h>

typedef __attribute__((ext_vector_type(8))) short short8;
typedef __attribute__((ext_vector_type(4))) float f32x4;
typedef __attribute__((ext_vector_type(4))) unsigned int u32x4;

struct XPtrs { const float* p[17]; };
struct Bases { int v[18]; };

#define CPB 8  // units (of 64 rows) per block; divides 128*L exactly

__device__ __forceinline__ unsigned short f2bf(float f) {
  unsigned u = __float_as_uint(f);
  return (unsigned short)((u + 0x7fffu + ((u >> 16) & 1u)) >> 16);  // RNE
}

// ---------------- pre-kernel: W fp32 -> bf16, fragment-packed into ws ----
// Per diag d: 2048 slots of 16 B. slot = sg*128 + n  (sg = s*4 + g)
// slot holds W[d][n][k] for k = sg*8 .. sg*8+7 as 8 bf16 (RNE).
__global__ __launch_bounds__(1024) void convert_w_kernel(
    const float* __restrict__ W, unsigned short* __restrict__ ws) {
  const int tid = blockIdx.x * 1024 + threadIdx.x;  // 0 .. 17*2048-1
  const int d  = tid >> 11;
  const int s2 = tid & 2047;
  const int sg = s2 >> 7;     // 0..15
  const int n  = s2 & 127;
  const float* src = W + ((size_t)d * 128 + n) * 128 + sg * 8;
  float4 a = *(const float4*)(src);
  float4 b = *(const float4*)(src + 4);
  unsigned u0 = (unsigned)f2bf(a.x) | ((unsigned)f2bf(a.y) << 16);
  unsigned u1 = (unsigned)f2bf(a.z) | ((unsigned)f2bf(a.w) << 16);
  unsigned u2 = (unsigned)f2bf(b.x) | ((unsigned)f2bf(b.y) << 16);
  unsigned u3 = (unsigned)f2bf(b.z) | ((unsigned)f2bf(b.w) << 16);
  *(uint4*)(ws + (size_t)tid * 8) = make_uint4(u0, u1, u2, u3);
}

// pack two fp32 -> u32 of two bf16, round-half-up (cheap; for X)
__device__ __forceinline__ unsigned pack_bf2(float lo, float hi) {
  unsigned rl = __float_as_uint(lo) + 0x8000u;
  unsigned rh = __float_as_uint(hi) + 0x8000u;
  return __builtin_amdgcn_perm(rh, rl, 0x07060302u);  // {rh[31:16], rl[31:16]}
}

__device__ __forceinline__ void issue_unit_loads(
    const float* __restrict__ x, int u, int wave, int lr, int lg,
    float4 (&pf)[8]) {
  const float* xr = x + ((size_t)(u * 64 + wave * 16 + lr)) * 128 + lg * 8;
#pragma unroll
  for (int s = 0; s < 4; ++s) {
    pf[2 * s]     = *(const float4*)(xr + s * 32);
    pf[2 * s + 1] = *(const float4*)(xr + s * 32 + 4);
  }
}

__device__ __forceinline__ void convert_unit(const float4 (&pf)[8],
                                             short8 (&xf)[4]) {
#pragma unroll
  for (int s = 0; s < 4; ++s) {
    float4 a0 = pf[2 * s], a1 = pf[2 * s + 1];
    u32x4 w;
    w.x = pack_bf2(a0.x, a0.y);
    w.y = pack_bf2(a0.z, a0.w);
    w.z = pack_bf2(a1.x, a1.y);
    w.w = pack_bf2(a1.z, a1.w);
    xf[s] = __builtin_bit_cast(short8, w);
  }
}

// compute + store one unit: nb-outer, s-inner; store acc[nb] right after its
// 4 MFMAs -> ~1 acc vector live at a time. setprio(1) keeps the MFMA burst
// fed so this wave returns to load-issue sooner (waves are independent).
__device__ __forceinline__ void compute_store_unit(
    const short8 (&xf)[4], const unsigned short* __restrict__ wlds,
    const float* __restrict__ blds, int u, int wave, int lr, int lg,
    int L, int start, int d, float* __restrict__ out) {
  const int f = u * 64 + wave * 16 + lr;
  const unsigned b = (unsigned)f / (unsigned)L;
  const int l = f - (int)b * L;
  float* orow = out + (size_t)b * 10368 + (size_t)(start * 8 + d) * 128
                + (size_t)l * 1024 + lg * 4;
  __builtin_amdgcn_s_setprio(1);
#pragma unroll
  for (int nb = 0; nb < 8; ++nb) {
    f32x4 acc = *(const f32x4*)&blds[nb * 16 + lg * 4];   // bias init (LDS)
#pragma unroll
    for (int s = 0; s < 4; ++s) {
      short8 wf = *(const short8*)
          &wlds[(size_t)((s * 4 + lg) * 128 + nb * 16 + lr) * 8];
      acc = __builtin_amdgcn_mfma_f32_16x16x32_bf16(wf, xf[s], acc, 0, 0, 0);
    }
    *(f32x4*)(orow + nb * 16) = acc;
  }
  __builtin_amdgcn_s_setprio(0);
}

// ---------------- main kernel ----------------
// 256 threads = 4 waves. Block owns CPB units of 64 rows in ONE diagonal.
// W+bias staged to LDS once. Steady state: 2-deep double-buffered register
// prefetch (static pA/pB). Waves process units in ROTATED order (stride 2*w)
// to decorrelate their load-wait phases on the SIMDs.
__global__ __launch_bounds__(256) void diag_linear_kernel(
    XPtrs xp, Bases bb, const unsigned short* __restrict__ wsrc,
    const float* __restrict__ bias, float* __restrict__ out) {
  const int bid = blockIdx.x;
  int d = 0;
#pragma unroll
  for (int i = 1; i < 17; ++i) d += (bid >= bb.v[i]) ? 1 : 0;
  const int L = 9 - ((d < 8) ? (8 - d) : (d - 8));
  const int start = (d > 8) ? (d - 8) : 0;
  const float* __restrict__ x = xp.p[d];
  const int u0 = (bid - bb.v[d]) * CPB;

  const int t = threadIdx.x;
  const int lane = t & 63;
  const int wave = t >> 6;       // 0..3
  const int lr = lane & 15;
  const int lg = lane >> 4;
  const int rot = 2 * wave;      // per-wave unit rotation offset

  __shared__ unsigned short wlds[2048 * 8];  // 32 KiB
  __shared__ float blds[128];                // bias

  // ---- stage W[d] (pre-packed bf16) + bias via async global->LDS ----
  {
    const unsigned short* gw = wsrc + (size_t)d * 16384;
    typedef const __attribute__((address_space(1))) unsigned int* gas_u32;
    typedef __attribute__((address_space(3))) unsigned int* las_u32;
#pragma unroll
    for (int r = 0; r < 8; ++r) {
      const int slotbase = (wave * 8 + r) * 64;
      __builtin_amdgcn_global_load_lds(
          (gas_u32)(const void*)(gw + (size_t)(slotbase + lane) * 8),
          (las_u32)(void*)(wlds + (size_t)slotbase * 8),
          16, 0, 0);
    }
    if (t < 32) {  // lanes 0..31 -> blds[0..127], 16B/lane
      __builtin_amdgcn_global_load_lds(
          (gas_u32)(const void*)(bias + d * 128 + t * 4),
          (las_u32)(void*)(blds), 16, 0, 0);
    }
  }

  // rotated unit sequence: seq(it) = u0 + ((it + rot) & 7)
#define SEQ(IT) (u0 + (((IT) + rot) & (CPB - 1)))

  // ---- prologue: 2 units in flight (overlaps W staging) ----
  float4 pA[8], pB[8];
  issue_unit_loads(x, SEQ(0), wave, lr, lg, pA);
  issue_unit_loads(x, SEQ(1), wave, lr, lg, pB);

  __syncthreads();   // W + bias resident

#pragma unroll 1
  for (int k = 0; k < CPB / 2; ++k) {
    // ---- A phase (it = 2k) ----
    {
      short8 xf[4];
      convert_unit(pA, xf);
      if (2 * k + 2 < CPB)
        issue_unit_loads(x, SEQ(2 * k + 2), wave, lr, lg, pA);
      compute_store_unit(xf, wlds, blds, SEQ(2 * k), wave, lr, lg,
                         L, start, d, out);
    }
    // ---- B phase (it = 2k+1) ----
    {
      short8 xf[4];
      convert_unit(pB, xf);
      if (2 * k + 3 < CPB)
        issue_unit_loads(x, SEQ(2 * k + 3), wave, lr, lg, pB);
      compute_store_unit(xf, wlds, blds, SEQ(2 * k + 1), wave, lr, lg,
                         L, start, d, out);
    }
  }
#undef SEQ
}

extern "C" void kernel_launch(void* const* d_in, const int* in_sizes, int n_in,
                              void* d_out, int out_size, void* d_ws, size_t ws_size,
                              hipStream_t stream) {
  const float* W = (const float*)d_in[0];
  const float* bias = (const float*)d_in[1];
  XPtrs xp;
  for (int i = 0; i < 17; ++i) xp.p[i] = (const float*)d_in[2 + i];
  float* out = (float*)d_out;
  unsigned short* ws = (unsigned short*)d_ws;   // 17*2048*16 B = 544 KiB

  Bases bb;
  int base = 0;
  for (int i = 0; i < 17; ++i) {
    bb.v[i] = base;
    int L = 9 - ((i < 8) ? (8 - i) : (i - 8));
    base += (128 * L) / CPB;     // 16*L blocks per diag, exact
  }
  bb.v[17] = base;               // 1296 blocks

  convert_w_kernel<<<34, 1024, 0, stream>>>(W, ws);
  diag_linear_kernel<<<base, 256, 0, stream>>>(xp, bb, ws, bias, out);
}

// Round 11
// 146.176 us; speedup vs baseline: 1.0913x; 1.0913x over previous
//
#include <hip/hip_runtime.h>
#include <hip/hip_bf16.h>

typedef __attribute__((ext_vector_type(8))) short short8;
typedef __attribute__((ext_vector_type(4))) float f32x4;
typedef __attribute__((ext_vector_type(4))) unsigned int u32x4;

struct XPtrs { const float* p[17]; };
struct Bases { int v[18]; };

#define CPB 2  // units (of 64 rows) per block; divides 128*L exactly

__device__ __forceinline__ unsigned short f2bf(float f) {
  unsigned u = __float_as_uint(f);
  return (unsigned short)((u + 0x7fffu + ((u >> 16) & 1u)) >> 16);  // RNE
}

// ---------------- pre-kernel: W fp32 -> bf16, fragment-packed into ws ----
// Per diag d: 2048 slots of 16 B. slot = sg*128 + n  (sg = s*4 + g)
// slot holds W[d][n][k] for k = sg*8 .. sg*8+7 as 8 bf16 (RNE).
__global__ __launch_bounds__(1024) void convert_w_kernel(
    const float* __restrict__ W, unsigned short* __restrict__ ws) {
  const int tid = blockIdx.x * 1024 + threadIdx.x;  // 0 .. 17*2048-1
  const int d  = tid >> 11;
  const int s2 = tid & 2047;
  const int sg = s2 >> 7;     // 0..15
  const int n  = s2 & 127;
  const float* src = W + ((size_t)d * 128 + n) * 128 + sg * 8;
  float4 a = *(const float4*)(src);
  float4 b = *(const float4*)(src + 4);
  unsigned u0 = (unsigned)f2bf(a.x) | ((unsigned)f2bf(a.y) << 16);
  unsigned u1 = (unsigned)f2bf(a.z) | ((unsigned)f2bf(a.w) << 16);
  unsigned u2 = (unsigned)f2bf(b.x) | ((unsigned)f2bf(b.y) << 16);
  unsigned u3 = (unsigned)f2bf(b.z) | ((unsigned)f2bf(b.w) << 16);
  *(uint4*)(ws + (size_t)tid * 8) = make_uint4(u0, u1, u2, u3);
}

// pack two fp32 -> u32 of two bf16, round-half-up (cheap; for X)
__device__ __forceinline__ unsigned pack_bf2(float lo, float hi) {
  unsigned rl = __float_as_uint(lo) + 0x8000u;
  unsigned rh = __float_as_uint(hi) + 0x8000u;
  return __builtin_amdgcn_perm(rh, rl, 0x07060302u);  // {rh[31:16], rl[31:16]}
}

__device__ __forceinline__ void issue_unit_loads(
    const float* __restrict__ x, int u, int wave, int lr, int lg,
    float4 (&pf)[8]) {
  const float* xr = x + ((size_t)(u * 64 + wave * 16 + lr)) * 128 + lg * 8;
#pragma unroll
  for (int s = 0; s < 4; ++s) {
    pf[2 * s]     = *(const float4*)(xr + s * 32);
    pf[2 * s + 1] = *(const float4*)(xr + s * 32 + 4);
  }
}

__device__ __forceinline__ void convert_unit(const float4 (&pf)[8],
                                             short8 (&xf)[4]) {
#pragma unroll
  for (int s = 0; s < 4; ++s) {
    float4 a0 = pf[2 * s], a1 = pf[2 * s + 1];
    u32x4 w;
    w.x = pack_bf2(a0.x, a0.y);
    w.y = pack_bf2(a0.z, a0.w);
    w.z = pack_bf2(a1.x, a1.y);
    w.w = pack_bf2(a1.z, a1.w);
    xf[s] = __builtin_bit_cast(short8, w);
  }
}

// compute + store one unit: nb-outer, s-inner; store acc[nb] right after its
// 4 MFMAs -> ~1 acc vector live at a time (keeps VGPR under the 128 cliff)
__device__ __forceinline__ void compute_store_unit(
    const short8 (&xf)[4], const unsigned short* __restrict__ wlds,
    const float* __restrict__ blds, int u, int wave, int lr, int lg,
    int L, int start, int d, float* __restrict__ out) {
  const int f = u * 64 + wave * 16 + lr;
  const unsigned b = (unsigned)f / (unsigned)L;
  const int l = f - (int)b * L;
  float* orow = out + (size_t)b * 10368 + (size_t)(start * 8 + d) * 128
                + (size_t)l * 1024 + lg * 4;
#pragma unroll
  for (int nb = 0; nb < 8; ++nb) {
    f32x4 acc = *(const f32x4*)&blds[nb * 16 + lg * 4];   // bias init (LDS)
#pragma unroll
    for (int s = 0; s < 4; ++s) {
      short8 wf = *(const short8*)
          &wlds[(size_t)((s * 4 + lg) * 128 + nb * 16 + lr) * 8];
      acc = __builtin_amdgcn_mfma_f32_16x16x32_bf16(wf, xf[s], acc, 0, 0, 0);
    }
    *(f32x4*)(orow + nb * 16) = acc;
  }
}

// ---------------- main kernel ----------------
// 256 threads = 4 waves. Block owns 2 units of 64 rows in ONE diagonal.
// Prologue: W (9 global_load_lds, oldest in VMEM queue) then BOTH units'
// X loads to registers. Barrier waits vmcnt(16) only -> W resident, X still
// in flight. Phase A consumes unit 0, phase B consumes unit 1. No reissue,
// no loop, minimal block quantum (smooth streaming tail).
__global__ __launch_bounds__(256) void diag_linear_kernel(
    XPtrs xp, Bases bb, const unsigned short* __restrict__ wsrc,
    const float* __restrict__ bias, float* __restrict__ out) {
  const int bid = blockIdx.x;
  int d = 0;
#pragma unroll
  for (int i = 1; i < 17; ++i) d += (bid >= bb.v[i]) ? 1 : 0;
  const int L = 9 - ((d < 8) ? (8 - d) : (d - 8));
  const int start = (d > 8) ? (d - 8) : 0;
  const float* __restrict__ x = xp.p[d];
  const int u0 = (bid - bb.v[d]) * CPB;

  const int t = threadIdx.x;
  const int lane = t & 63;
  const int wave = t >> 6;       // 0..3
  const int lr = lane & 15;
  const int lg = lane >> 4;

  __shared__ unsigned short wlds[2048 * 8];  // 32 KiB
  __shared__ float blds[128];                // bias

  // ---- stage W[d] (pre-packed bf16) + bias via async global->LDS ----
  // These 9 VMEM ops are issued FIRST (oldest) so vmcnt(16) below drains
  // exactly them while the 16 X loads stay outstanding.
  {
    const unsigned short* gw = wsrc + (size_t)d * 16384;
    typedef const __attribute__((address_space(1))) unsigned int* gas_u32;
    typedef __attribute__((address_space(3))) unsigned int* las_u32;
#pragma unroll
    for (int r = 0; r < 8; ++r) {
      const int slotbase = (wave * 8 + r) * 64;
      __builtin_amdgcn_global_load_lds(
          (gas_u32)(const void*)(gw + (size_t)(slotbase + lane) * 8),
          (las_u32)(void*)(wlds + (size_t)slotbase * 8),
          16, 0, 0);
    }
    if (t < 32) {  // lanes 0..31 -> blds[0..127], 16B/lane
      __builtin_amdgcn_global_load_lds(
          (gas_u32)(const void*)(bias + d * 128 + t * 4),
          (las_u32)(void*)(blds), 16, 0, 0);
    }
  }

  // ---- both units' X loads into registers (stay in flight across barrier)
  float4 pA[8], pB[8];
  issue_unit_loads(x, u0,     wave, lr, lg, pA);
  issue_unit_loads(x, u0 + 1, wave, lr, lg, pB);

  // ---- barrier that does NOT drain the X loads ----
  asm volatile("s_waitcnt vmcnt(16)" ::: "memory");   // W + bias resident
  __builtin_amdgcn_s_barrier();
  __builtin_amdgcn_sched_barrier(0);                  // rule #18 fence

  // ---- phase A: unit u0 ----
  {
    short8 xf[4];
    convert_unit(pA, xf);   // compiler-inserted vmcnt waits for pA only
    compute_store_unit(xf, wlds, blds, u0, wave, lr, lg, L, start, d, out);
  }
  // ---- phase B: unit u0+1 ----
  {
    short8 xf[4];
    convert_unit(pB, xf);
    compute_store_unit(xf, wlds, blds, u0 + 1, wave, lr, lg, L, start, d, out);
  }
}

extern "C" void kernel_launch(void* const* d_in, const int* in_sizes, int n_in,
                              void* d_out, int out_size, void* d_ws, size_t ws_size,
                              hipStream_t stream) {
  const float* W = (const float*)d_in[0];
  const float* bias = (const float*)d_in[1];
  XPtrs xp;
  for (int i = 0; i < 17; ++i) xp.p[i] = (const float*)d_in[2 + i];
  float* out = (float*)d_out;
  unsigned short* ws = (unsigned short*)d_ws;   // 17*2048*16 B = 544 KiB

  Bases bb;
  int base = 0;
  for (int i = 0; i < 17; ++i) {
    bb.v[i] = base;
    int L = 9 - ((i < 8) ? (8 - i) : (i - 8));
    base += (128 * L) / CPB;     // 64*L blocks per diag, exact
  }
  bb.v[17] = base;               // 5184 blocks

  convert_w_kernel<<<34, 1024, 0, stream>>>(W, ws);
  diag_linear_kernel<<<base, 256, 0, stream>>>(xp, bb, ws, bias, out);
}